// Round 6
// baseline (307.682 us; speedup 1.0000x reference)
//
#include <hip/hip_runtime.h>
#include <math.h>

// Problem constants
#define BATCH   8
#define QLEN    256
#define KLEN    2048
#define KDIM    512
#define ADIMC   512
#define NHEADS  4
#define DKH     128
#define CHUNKW  4

static constexpr float INV_SCALE = 0.04419417382415922f; // 1/sqrt(512)
static constexpr float EPSV = 1e-6f;

typedef __attribute__((ext_vector_type(8))) short bf16x8;
typedef __attribute__((ext_vector_type(4))) float f32x4;

__device__ __forceinline__ unsigned short f2bf(float f) {
    unsigned u = __builtin_bit_cast(unsigned, f);
    u += 0x7fffu + ((u >> 16) & 1u);   // round-to-nearest-even
    return (unsigned short)(u >> 16);
}

// Barrier waiting only on LDS ops (lgkmcnt); global loads/stores stay in flight.
__device__ __forceinline__ void lds_barrier() {
    __asm__ volatile("s_waitcnt lgkmcnt(0)\n\ts_barrier" ::: "memory");
}

// Async global->LDS, 16 B per lane (wave-uniform base + lane*16 rule).
__device__ __forceinline__ void gload_lds16(const void* g, void* l) {
    __builtin_amdgcn_global_load_lds(
        (const __attribute__((address_space(1))) void*)g,
        (__attribute__((address_space(3))) void*)l, 16, 0, 0);
}

// ---------------------------------------------------------------------------
// prep: fused input casts + weight transpose-casts (one launch instead of 6).
// ---------------------------------------------------------------------------
#define NKXB (BATCH * KLEN * KDIM / 4 / 256)   // 8192
#define NQXB (BATCH * QLEN * KDIM / 4 / 256)   // 1024
__global__ __launch_bounds__(256) void prep(
    const float* __restrict__ key_enc, const float* __restrict__ query,
    const float* __restrict__ Wk_m, const float* __restrict__ Wk_c,
    const float* __restrict__ Wq_m, const float* __restrict__ Wq_c,
    unsigned short* __restrict__ kx, unsigned short* __restrict__ qx,
    unsigned short* __restrict__ WTk, unsigned short* __restrict__ WTq)
{
    __shared__ float tile[32][33];
    const int gb = blockIdx.x;
    const int tid = threadIdx.x;

    if (gb < NKXB + NQXB) {
        const float* x = (gb < NKXB) ? key_enc : query;
        unsigned short* y = (gb < NKXB) ? kx : qx;
        const int i = (gb < NKXB ? gb : gb - NKXB) * 256 + tid;
        float4 v = ((const float4*)x)[i];
        ushort4 o;
        o.x = f2bf(v.x); o.y = f2bf(v.y); o.z = f2bf(v.z); o.w = f2bf(v.w);
        ((ushort4*)y)[i] = o;
        return;
    }
    const int t = gb - NKXB - NQXB;          // 0..1023
    const int which = t >> 8;                // 0..3
    const int tt = t & 255;
    const int bx = tt & 15, byy = tt >> 4;   // 16 x 16 tile grid
    const float* W = (which == 0) ? Wk_m : (which == 1) ? Wk_c
                   : (which == 2) ? Wq_m : Wq_c;
    unsigned short* WT = (which == 0) ? WTk
                       : (which == 1) ? WTk + (size_t)512 * KDIM
                       : (which == 2) ? WTq : WTq + (size_t)512 * KDIM;
    const int tx = tid & 31, ty = tid >> 5;  // 32 x 8
    const int k0 = byy * 32, n0 = bx * 32;
    #pragma unroll
    for (int i = 0; i < 32; i += 8)
        tile[ty + i][tx] = W[(size_t)(k0 + ty + i) * KDIM + n0 + tx];
    __syncthreads();
    #pragma unroll
    for (int i = 0; i < 32; i += 8)
        WT[(size_t)(n0 + ty + i) * KDIM + k0 + tx] = f2bf(tile[tx][ty + i]);
}

// ---------------------------------------------------------------------------
// Staged NT MFMA core: block computes 128x128 f32 tile of A[M,K] @ B[N,K]^T.
// 256 threads / 4 waves, each wave a 64x64 subtile.
// ---------------------------------------------------------------------------
template<int KSTEPS>
__device__ __forceinline__ void mfma_nt_staged(
    const unsigned short* __restrict__ A, const unsigned short* __restrict__ B,
    int lda, int ldb, int bm, int bn,
    unsigned short* AsLDS, unsigned short* BsLDS, f32x4 acc[4][4])
{
    const int t = threadIdx.x;
    const int wv = t >> 6, ln = t & 63;
    const int r = ln & 15, quad = ln >> 4;
    const int wm = (wv >> 1) * 64, wn = (wv & 1) * 64;
    const int srow = wv * 16 + (ln >> 2);
    const int scol = (ln & 3) * 8;

    for (int ks = 0; ks < KSTEPS; ++ks) {
        const int k0 = ks * 32;
        #pragma unroll
        for (int j = 0; j < 2; ++j) {
            gload_lds16(A + (size_t)(bm + j * 64 + srow) * lda + k0 + scol,
                        AsLDS + (size_t)(j * 64 + wv * 16) * 32);
            gload_lds16(B + (size_t)(bn + j * 64 + srow) * ldb + k0 + scol,
                        BsLDS + (size_t)(j * 64 + wv * 16) * 32);
        }
        __syncthreads();
        bf16x8 af[4], bg[4];
        #pragma unroll
        for (int f = 0; f < 4; ++f)
            af[f] = *(const bf16x8*)(AsLDS + (size_t)(wm + f * 16 + r) * 32 + quad * 8);
        #pragma unroll
        for (int f = 0; f < 4; ++f)
            bg[f] = *(const bf16x8*)(BsLDS + (size_t)(wn + f * 16 + r) * 32 + quad * 8);
        #pragma unroll
        for (int i = 0; i < 4; ++i)
            #pragma unroll
            for (int j2 = 0; j2 < 4; ++j2)
                acc[i][j2] = __builtin_amdgcn_mfma_f32_16x16x32_bf16(
                    af[i], bg[j2], acc[i][j2], 0, 0, 0);
        __syncthreads();
    }
}

__device__ __forceinline__ void zero_acc(f32x4 acc[4][4]) {
    #pragma unroll
    for (int i = 0; i < 4; ++i)
        #pragma unroll
        for (int j = 0; j < 4; ++j)
            acc[i][j] = f32x4{0.f, 0.f, 0.f, 0.f};
}

// ---------------------------------------------------------------------------
// Projection (merged k+q): C[M x 1024] bf16 = A[M x 512] @ WT[1024 x 512]^T + b
// ---------------------------------------------------------------------------
__global__ __launch_bounds__(256) void proj_mfma(
    const unsigned short* __restrict__ kx, const unsigned short* __restrict__ qx,
    const unsigned short* __restrict__ WTk, const unsigned short* __restrict__ WTq,
    const float* __restrict__ bk_m, const float* __restrict__ bk_c,
    const float* __restrict__ bq_m, const float* __restrict__ bq_c,
    unsigned short* __restrict__ kproj, unsigned short* __restrict__ qproj)
{
    __shared__ unsigned short As[128 * 32];
    __shared__ unsigned short Bs[128 * 32];
    const int by = blockIdx.y;
    const unsigned short *A, *WT;
    unsigned short* C;
    const float *bm_, *bc_;
    int bm;
    if (by < 128) { A = kx; WT = WTk; C = kproj; bm_ = bk_m; bc_ = bk_c; bm = by * 128; }
    else          { A = qx; WT = WTq; C = qproj; bm_ = bq_m; bc_ = bq_c; bm = (by - 128) * 128; }
    const int bn = blockIdx.x * 128;
    f32x4 acc[4][4]; zero_acc(acc);
    mfma_nt_staged<16>(A, WT, KDIM, KDIM, bm, bn, As, Bs, acc);
    const int wv = threadIdx.x >> 6, ln = threadIdx.x & 63;
    const int r = ln & 15, quad = ln >> 4;
    const int m0 = bm + (wv >> 1) * 64, n0 = bn + (wv & 1) * 64;
    #pragma unroll
    for (int j = 0; j < 4; ++j) {
        const int n = n0 + j * 16 + r;
        const float bv = (n < 512) ? bm_[n] : bc_[n - 512];
        #pragma unroll
        for (int i = 0; i < 4; ++i) {
            #pragma unroll
            for (int reg = 0; reg < 4; ++reg) {
                const int m = m0 + i * 16 + quad * 4 + reg;
                C[(size_t)m * 1024 + n] = f2bf(acc[i][j][reg] + bv);
            }
        }
    }
}

// ---------------------------------------------------------------------------
// p_choose: per batch b, p = sigmoid(qm[b] @ km[b]^T / sqrt(512) + r + noise)
// ---------------------------------------------------------------------------
__global__ __launch_bounds__(256) void pchoose_mfma(
    const unsigned short* __restrict__ qp, const unsigned short* __restrict__ kp,
    const float* __restrict__ noise, const float* __restrict__ rp,
    float* __restrict__ p)
{
    __shared__ unsigned short As[128 * 32];
    __shared__ unsigned short Bs[128 * 32];
    const int b = blockIdx.z;
    const unsigned short* A = qp + (size_t)b * QLEN * 1024;
    const unsigned short* B = kp + (size_t)b * KLEN * 1024;
    const int bm = blockIdx.y * 128, bn = blockIdx.x * 128;
    f32x4 acc[4][4]; zero_acc(acc);
    mfma_nt_staged<16>(A, B, 1024, 1024, bm, bn, As, Bs, acc);
    const int wv = threadIdx.x >> 6, ln = threadIdx.x & 63;
    const int r = ln & 15, quad = ln >> 4;
    const int m0 = bm + (wv >> 1) * 64, n0 = bn + (wv & 1) * 64;
    const float rv = rp[0];
    #pragma unroll
    for (int i = 0; i < 4; ++i) {
        #pragma unroll
        for (int reg = 0; reg < 4; ++reg) {
            const int q = m0 + i * 16 + quad * 4 + reg;
            const size_t rowoff = ((size_t)b * QLEN + q) * KLEN;
            #pragma unroll
            for (int j = 0; j < 4; ++j) {
                const int k = n0 + j * 16 + r;
                const float e = acc[i][j][reg] * INV_SCALE + rv + noise[rowoff + k];
                p[rowoff + k] = __builtin_amdgcn_rcpf(1.0f + __expf(-e));
            }
        }
    }
}

// ---------------------------------------------------------------------------
// 64-lane inclusive prefix sum via DPP (≈6 VALU ops)
// ---------------------------------------------------------------------------
__device__ __forceinline__ float wave_incl_scan(float x)
{
#define DPP_ADD(ctrl, rmask, bctrl)                                            \
    { int _t = __builtin_amdgcn_update_dpp(0, __builtin_bit_cast(int, x),      \
                                           ctrl, rmask, 0xf, bctrl);           \
      x += __builtin_bit_cast(float, _t); }
    DPP_ADD(0x111, 0xf, true)   // row_shr:1
    DPP_ADD(0x112, 0xf, true)   // row_shr:2
    DPP_ADD(0x114, 0xf, true)   // row_shr:4
    DPP_ADD(0x118, 0xf, true)   // row_shr:8
    DPP_ADD(0x142, 0xa, false)  // row_bcast:15 -> rows 1,3
    DPP_ADD(0x143, 0xc, false)  // row_bcast:31 -> rows 2,3
#undef DPP_ADD
    return x;
}

// ---------------------------------------------------------------------------
// cumprod_mr: per (b,q) row: cp = exp(excl_cumsum(log(clip(1-p)))); emits
// m = p*cp, r = 1/clip(cp). Fast intrinsics; absorbs all transcendentals.
// ---------------------------------------------------------------------------
__global__ __launch_bounds__(256) void cumprod_mr(
    const float* __restrict__ p, float* __restrict__ mArr, float* __restrict__ rArr)
{
    const size_t row = blockIdx.x;
    const float* pr = p + row * KLEN;
    float* mr = mArr + row * KLEN;
    float* rr = rArr + row * KLEN;
    const int tid = threadIdx.x;
    const int lane = tid & 63, wid = tid >> 6;
    __shared__ float waveTot[4];

    float4 v0 = *(const float4*)(pr + tid * 8);
    float4 v1 = *(const float4*)(pr + tid * 8 + 4);
    float pv[8] = {v0.x, v0.y, v0.z, v0.w, v1.x, v1.y, v1.z, v1.w};
    float excl[8];
    float run = 0.0f;
    #pragma unroll
    for (int j = 0; j < 8; ++j) {
        float l = __logf(fminf(fmaxf(1.0f - pv[j], EPSV), 1.0f));
        excl[j] = run;
        run += l;
    }
    float s = wave_incl_scan(run);
    if (lane == 63) waveTot[wid] = s;
    __syncthreads();
    float wex = 0.0f;
    for (int w = 0; w < wid; ++w) wex += waveTot[w];
    const float texcl = wex + s - run;

    float mv[8], rv[8];
    #pragma unroll
    for (int j = 0; j < 8; ++j) {
        const float cpv = __expf(texcl + excl[j]);
        mv[j] = pv[j] * cpv;
        rv[j] = __builtin_amdgcn_rcpf(fminf(fmaxf(cpv, EPSV), 1.0f));
    }
    *(float4*)(mr + tid * 8)     = *(float4*)&mv[0];
    *(float4*)(mr + tid * 8 + 4) = *(float4*)&mv[4];
    *(float4*)(rr + tid * 8)     = *(float4*)&rv[0];
    *(float4*)(rr + tid * 8 + 4) = *(float4*)&rv[4];
}

// ---------------------------------------------------------------------------
// alpha_echunk: FUSED kernel, 512 threads.
//  Blocks 0..7: alpha recurrence, 8 waves, PUBLISH-EARLY linearized exchange.
//    R5 evidence: the ~835cyc/step is the serial round-trip (write->barrier->
//    read) INSIDE the dependency loop, not barrier population. Linearity fix:
//    with u_i = m_i*r_{i+1}, G_i = C_i + s_i, the NEXT step's wave total is
//    T_w^{(i+1)} = total(u_i * G_i) — computable THIS step. Each wave
//    publishes T^{(i+1)} into slot[(i+1)&1] at step i; at step i+1 the
//    broadcast read of slot[(i+1)&1] is issued at step START and its latency
//    hides under the chain+scan. The barrier remains only as the slot-swap
//    fence (race-free: write slot[(i+1)&1] after the step-i barrier; that
//    slot was last read at step i-1, before it). Serial spine per step:
//    chain(4 fmaf) -> scan(6 DPP) -> G -> y-chain -> y-scan -> write. All
//    quantities are positive sums -> regrouping is numerically benign.
//  Blocks 8..1031: e_chunk MFMA tiles (R3 form: tid<256 workers).
//  smem 96 KB -> 1 block/CU isolation (+4% proven, kept). setprio kept.
// ---------------------------------------------------------------------------
__global__ __launch_bounds__(512, 1) void alpha_echunk(
    const float* __restrict__ mArr, const float* __restrict__ rArr,
    float* __restrict__ alpha,
    const unsigned short* __restrict__ qp, const unsigned short* __restrict__ kp,
    float* __restrict__ out)
{
    __shared__ __align__(16) char smem[98304];   // 96 KB -> 1 block/CU
    const int bid = blockIdx.x;
    const int tid = threadIdx.x;

    if (bid < BATCH) {
        // ------ alpha scan: publish-early linearized exchange ------
        __builtin_amdgcn_s_setprio(1);
        float* slots = (float*)smem;             // [2][8]
        const int lane = tid & 63, wid = tid >> 6;
        const float* mrow = mArr + (size_t)bid * QLEN * KLEN + tid * 4;
        const float* rrow = rArr + (size_t)bid * QLEN * KLEN + tid * 4;
        float* arow = alpha + (size_t)bid * QLEN * KLEN + tid * 4;

        // initial state
        float4 uP = *(const float4*)(rrow);              // u_{-1} = r_0
        float4 mA = *(const float4*)(mrow);              // m_0  (step 0)
        float4 rA = *(const float4*)(rrow + KLEN);       // r_1  (step 0)
        float4 mB = *(const float4*)(mrow + KLEN);       // m_1  (step 1)
        float4 rB = *(const float4*)(rrow + 2 * KLEN);   // r_2  (step 1)
        float4 sP;                                       // s_{-1} = aw_init
        sP.x = (tid == 0) ? 1.0f : 0.0f; sP.y = 0.f; sP.z = 0.f; sP.w = 0.f;
        float Cw = 0.0f;                                 // C_{-1,w}

        if (tid < 16) slots[tid] = 0.0f;
        lds_barrier();
        if (tid == 0) slots[0] = uP.x;   // T^{(0)}_0 = r_0[0]; others 0
        lds_barrier();

#define ASTEP(I, M, R)                                                         \
    {                                                                          \
        const int i_ = (I);                                                    \
        /* broadcast read of this step's wave totals (issued early) */         \
        float4 t0 = *(const float4*)(slots + (i_ & 1) * 8);                    \
        float4 t1 = *(const float4*)(slots + (i_ & 1) * 8 + 4);                \
        float4 mc = M, rn = R;                                                 \
        const int rm_ = (i_ + 2 < QLEN) ? (i_ + 2) : (QLEN - 1);               \
        const int rr_ = (i_ + 3 < QLEN) ? (i_ + 3) : (QLEN - 1);               \
        M = *(const float4*)(mrow + (size_t)rm_ * KLEN);                       \
        R = *(const float4*)(rrow + (size_t)rr_ * KLEN);                       \
        /* x = u_{i-1} * (C_{i-1,w} + s_{i-1}); in-lane inclusive chain */     \
        float c0 = uP.x * (Cw + sP.x);                                         \
        float c1 = fmaf(uP.y, Cw + sP.y, c0);                                  \
        float c2 = fmaf(uP.z, Cw + sP.z, c1);                                  \
        float c3 = fmaf(uP.w, Cw + sP.w, c2);                                  \
        const float runx = c3;                                                 \
        const float scx = wave_incl_scan(runx);                                \
        /* cross-wave base from stale totals (off critical path) */            \
        float Ci = 0.0f;                                                       \
        if (wid > 0) Ci += t0.x;                                               \
        if (wid > 1) Ci += t0.y;                                               \
        if (wid > 2) Ci += t0.z;                                               \
        if (wid > 3) Ci += t0.w;                                               \
        if (wid > 4) Ci += t1.x;                                               \
        if (wid > 5) Ci += t1.y;                                               \
        if (wid > 6) Ci += t1.z;                                               \
        /* u_i (independent) */                                                \
        float4 u;                                                              \
        u.x = mc.x * rn.x; u.y = mc.y * rn.y;                                  \
        u.z = mc.z * rn.z; u.w = mc.w * rn.w;                                  \
        /* G = C_i + s_i */                                                    \
        const float bb = Ci + (scx - runx);                                    \
        const float G0 = bb + c0, G1 = bb + c1, G2 = bb + c2, G3 = bb + c3;    \
        /* publish next step's wave total: T^{(i+1)}_w = total(u_i * G_i) */   \
        float ys = u.x * G0;                                                   \
        ys = fmaf(u.y, G1, ys);                                                \
        ys = fmaf(u.z, G2, ys);                                                \
        ys = fmaf(u.w, G3, ys);                                                \
        const float sy = wave_incl_scan(ys);                                   \
        if (lane == 63) slots[((i_ + 1) & 1) * 8 + wid] = sy;                  \
        /* alpha output */                                                     \
        float4 ov;                                                             \
        ov.x = mc.x * G0; ov.y = mc.y * G1;                                    \
        ov.z = mc.z * G2; ov.w = mc.w * G3;                                    \
        *(float4*)(arow + (size_t)i_ * KLEN) = ov;                             \
        /* state update */                                                     \
        const float sb = scx - runx;                                           \
        sP.x = sb + c0; sP.y = sb + c1; sP.z = sb + c2; sP.w = sb + c3;        \
        uP = u; Cw = Ci;                                                       \
        lds_barrier();                                                         \
    }

        for (int io = 0; io < QLEN; io += 2) {
            ASTEP(io + 0, mA, rA)
            ASTEP(io + 1, mB, rB)
        }
#undef ASTEP
        __builtin_amdgcn_s_setprio(0);
        return;
    }

    // ---------------- echunk tile (512 threads, tid<256 workers) -----------
    const int v = bid - BATCH;           // 0..1023
    const int z = v >> 5;                // 0..31 = b*4+h
    const int by = (v >> 4) & 1;
    const int bx = v & 15;
    const int b = z >> 2, h = z & 3;
    const bool worker = tid < 256;
    unsigned short* As = (unsigned short*)smem;            // 8 KB
    unsigned short* Bs = (unsigned short*)(smem + 8192);   // 8 KB
    const unsigned short* A = qp + (size_t)b * QLEN * 1024 + 512 + h * DKH;
    const unsigned short* B = kp + (size_t)b * KLEN * 1024 + 512 + h * DKH;
    const int bm = by * 128, bn = bx * 128;

    const int wv = tid >> 6, ln = tid & 63;
    const int r = ln & 15, quad = ln >> 4;
    const int wm = (wv >> 1) * 64, wn = (wv & 1) * 64;
    const int srow = (wv & 3) * 16 + (ln >> 2);
    const int scol = (ln & 3) * 8;

    f32x4 acc[4][4]; zero_acc(acc);
    for (int ks = 0; ks < 4; ++ks) {
        const int k0 = ks * 32;
        if (worker) {
            #pragma unroll
            for (int j = 0; j < 2; ++j) {
                gload_lds16(A + (size_t)(bm + j * 64 + srow) * 1024 + k0 + scol,
                            As + (size_t)(j * 64 + wv * 16) * 32);
                gload_lds16(B + (size_t)(bn + j * 64 + srow) * 1024 + k0 + scol,
                            Bs + (size_t)(j * 64 + wv * 16) * 32);
            }
        }
        __syncthreads();
        if (worker) {
            bf16x8 af[4], bg[4];
            #pragma unroll
            for (int f = 0; f < 4; ++f)
                af[f] = *(const bf16x8*)(As + (size_t)(wm + f * 16 + r) * 32 + quad * 8);
            #pragma unroll
            for (int f = 0; f < 4; ++f)
                bg[f] = *(const bf16x8*)(Bs + (size_t)(wn + f * 16 + r) * 32 + quad * 8);
            #pragma unroll
            for (int i = 0; i < 4; ++i)
                #pragma unroll
                for (int j2 = 0; j2 < 4; ++j2)
                    acc[i][j2] = __builtin_amdgcn_mfma_f32_16x16x32_bf16(
                        af[i], bg[j2], acc[i][j2], 0, 0, 0);
        }
        __syncthreads();
    }
    if (worker) {
        const int m0 = bm + (wv >> 1) * 64, n0 = bn + (wv & 1) * 64;
        #pragma unroll
        for (int i = 0; i < 4; ++i) {
            #pragma unroll
            for (int reg = 0; reg < 4; ++reg) {
                const int q = m0 + i * 16 + quad * 4 + reg;
                const size_t rowoff = ((size_t)z * QLEN + q) * KLEN;
                #pragma unroll
                for (int j = 0; j < 4; ++j) {
                    const int k = n0 + j * 16 + r;
                    out[rowoff + k] = acc[i][j][reg] * INV_SCALE;
                }
            }
        }
    }
}

// ---------------------------------------------------------------------------
// beta: per (b,h,q) row of 2048 (e_chunk in d_out, overwritten)
// ---------------------------------------------------------------------------
__global__ __launch_bounds__(256) void beta_kernel(
    float* __restrict__ eo, const float* __restrict__ alpha)
{
    __shared__ float sse[KLEN + 3];
    __shared__ float su[KLEN + 3];
    __shared__ float wmax[4];

    const int tid = threadIdx.x;
    const int lane = tid & 63, wid = tid >> 6;
    const int row = blockIdx.x;                 // [B*H*Q]
    const int q = row & (QLEN - 1);
    const int b = row >> 10;
    float* erow = eo + (size_t)row * KLEN;
    const float* arow = alpha + ((size_t)b * QLEN + q) * KLEN;

    if (tid < 3) { sse[tid] = 0.0f; su[KLEN + tid] = 0.0f; }

    float ev[8];
    float lm = -INFINITY;
    #pragma unroll
    for (int j = 0; j < 8; ++j) {
        const int k = tid + 256 * j;
        ev[j] = erow[k];
        lm = fmaxf(lm, ev[j]);
    }
    #pragma unroll
    for (int off = 32; off > 0; off >>= 1) lm = fmaxf(lm, __shfl_xor(lm, off));
    if (lane == 0) wmax[wid] = lm;
    __syncthreads();
    const float mx = fmaxf(fmaxf(wmax[0], wmax[1]), fmaxf(wmax[2], wmax[3]));

    #pragma unroll
    for (int j = 0; j < 8; ++j) {
        const int k = tid + 256 * j;
        sse[k + 3] = fmaxf(__expf(ev[j] - mx), 1e-5f);
    }
    __syncthreads();

    #pragma unroll
    for (int j = 0; j < 8; ++j) {
        const int k = tid + 256 * j;
        const float denom = sse[k + 3] + sse[k + 2] + sse[k + 1] + sse[k];
        su[k] = arow[k] * __builtin_amdgcn_rcpf(denom);
    }
    __syncthreads();

    #pragma unroll
    for (int j = 0; j < 8; ++j) {
        const int k = tid + 256 * j;
        erow[k] = sse[k + 3] * (su[k] + su[k + 1] + su[k + 2] + su[k + 3]);
    }
}

// ---------------------------------------------------------------------------
extern "C" void kernel_launch(void* const* d_in, const int* in_sizes, int n_in,
                              void* d_out, int out_size, void* d_ws, size_t ws_size,
                              hipStream_t stream)
{
    (void)in_sizes; (void)n_in; (void)out_size; (void)ws_size;
    const float* key_enc = (const float*)d_in[0];   // [8,2048,512]
    const float* query   = (const float*)d_in[1];   // [8,256,512]
    const float* noise   = (const float*)d_in[2];   // [8,256,2048]
    const float* Wk_m    = (const float*)d_in[3];
    const float* bk_m    = (const float*)d_in[4];
    const float* Wq_m    = (const float*)d_in[5];
    const float* bq_m    = (const float*)d_in[6];
    const float* rp      = (const float*)d_in[7];
    const float* Wk_c    = (const float*)d_in[8];
    const float* bk_c    = (const float*)d_in[9];
    const float* Wq_c    = (const float*)d_in[10];
    const float* bq_c    = (const float*)d_in[11];
    float* out = (float*)d_out;                     // [8,4,256,2048]

    // workspace layout (bytes)
    char* w = (char*)d_ws;
    unsigned short* kx    = (unsigned short*)w; w += (size_t)BATCH * KLEN * KDIM * 2;   // 16.8 MB
    unsigned short* qx    = (unsigned short*)w; w += (size_t)BATCH * QLEN * KDIM * 2;   //  2.1 MB
    unsigned short* WTk   = (unsigned short*)w; w += (size_t)1024 * KDIM * 2;           //  1.0 MB
    unsigned short* WTq   = (unsigned short*)w; w += (size_t)1024 * KDIM * 2;           //  1.0 MB
    unsigned short* kproj = (unsigned short*)w; w += (size_t)BATCH * KLEN * 1024 * 2;   // 33.6 MB
    unsigned short* qproj = (unsigned short*)w; w += (size_t)BATCH * QLEN * 1024 * 2;   //  4.2 MB
    float* p_alpha = (float*)w; w += (size_t)BATCH * QLEN * KLEN * 4;                   // 16.8 MB
    float* mArr    = (float*)w; w += (size_t)BATCH * QLEN * KLEN * 4;                   // 16.8 MB
    float* rArr    = (float*)w;                                                         // 16.8 MB

    // 1) fused prep: casts + weight transposes (1 launch)
    hipLaunchKernelGGL(prep, dim3(NKXB + NQXB + 1024), dim3(256), 0, stream,
                       key_enc, query, Wk_m, Wk_c, Wq_m, Wq_c,
                       kx, qx, WTk, WTq);

    // 2) projections, k+q merged (1 launch)
    hipLaunchKernelGGL(proj_mfma, dim3(8, BATCH * KLEN / 128 + BATCH * QLEN / 128),
                       dim3(256), 0, stream,
                       kx, qx, WTk, WTq, bk_m, bk_c, bq_m, bq_c, kproj, qproj);

    // 3) p_choose (staged bf16 MFMA + fast sigmoid epilogue)
    hipLaunchKernelGGL(pchoose_mfma, dim3(KLEN / 128, QLEN / 128, BATCH), dim3(256), 0, stream,
                       qproj, kproj, noise, rp, p_alpha);

    // 4) cumprod -> (m, r)  (parallel, absorbs all transcendentals)
    hipLaunchKernelGGL(cumprod_mr, dim3(BATCH * QLEN), dim3(256), 0, stream,
                       p_alpha, mArr, rArr);

    // 5) FUSED: alpha recurrence (blocks 0..7, publish-early pipeline) +
    //           e_chunk (blocks 8..1031)
    hipLaunchKernelGGL(alpha_echunk, dim3(BATCH + KLEN / 128 * QLEN / 128 * BATCH * NHEADS),
                       dim3(512), 0, stream,
                       mArr, rArr, p_alpha, qproj, kproj, out);

    // 6) beta (overwrites e_chunk rows in d_out)
    hipLaunchKernelGGL(beta_kernel, dim3(BATCH * NHEADS * QLEN), dim3(256), 0, stream,
                       out, p_alpha);
}

// Round 7
// 282.942 us; speedup vs baseline: 1.0874x; 1.0874x over previous
//
#include <hip/hip_runtime.h>
#include <math.h>

// Problem constants
#define BATCH   8
#define QLEN    256
#define KLEN    2048
#define KDIM    512
#define NHEADS  4
#define DKH     128
#define NG      5                       // mono + 4 heads
#define QROWS   (BATCH * QLEN)          // 2048
#define GCOLS   (NG * 512)              // 2560

static constexpr float INV_SCALE = 0.04419417382415922f; // 1/sqrt(512)
static constexpr float EPSV = 1e-6f;

typedef __attribute__((ext_vector_type(8))) short bf16x8;
typedef __attribute__((ext_vector_type(4))) float f32x4;

__device__ __forceinline__ unsigned short f2bf(float f) {
    unsigned u = __builtin_bit_cast(unsigned, f);
    u += 0x7fffu + ((u >> 16) & 1u);   // round-to-nearest-even
    return (unsigned short)(u >> 16);
}
__device__ __forceinline__ float bf2f(unsigned short u) {
    unsigned x = (unsigned)u << 16;
    return __builtin_bit_cast(float, x);
}

// Barrier waiting only on LDS ops (lgkmcnt); global loads/stores stay in flight.
__device__ __forceinline__ void lds_barrier() {
    __asm__ volatile("s_waitcnt lgkmcnt(0)\n\ts_barrier" ::: "memory");
}

// Async global->LDS, 16 B per lane (wave-uniform base + lane*16 rule).
__device__ __forceinline__ void gload_lds16(const void* g, void* l) {
    __builtin_amdgcn_global_load_lds(
        (const __attribute__((address_space(1))) void*)g,
        (__attribute__((address_space(3))) void*)l, 16, 0, 0);
}

// ---------------------------------------------------------------------------
// prep: all f32->bf16 casts in one launch. No transposes needed anymore:
// the G-GEMMs consume weights in natural [k][a] layout (NT contraction on a).
//  blocks [0, 8192)        cast key_enc -> kx
//  blocks [8192, 9216)     cast query   -> qx
//  blocks [9216, 10240)    cast the 4 weight matrices -> bf16
// ---------------------------------------------------------------------------
#define NKXB 8192
#define NQXB 1024
__global__ __launch_bounds__(256) void prep(
    const float* __restrict__ key_enc, const float* __restrict__ query,
    const float* __restrict__ Wk_m, const float* __restrict__ Wk_c,
    const float* __restrict__ Wq_m, const float* __restrict__ Wq_c,
    unsigned short* __restrict__ kx, unsigned short* __restrict__ qx,
    unsigned short* __restrict__ kwm, unsigned short* __restrict__ kwc,
    unsigned short* __restrict__ qwm, unsigned short* __restrict__ qwc)
{
    const int gb = blockIdx.x, tid = threadIdx.x;
    const float* x; unsigned short* y; int i;
    if (gb < NKXB)              { x = key_enc; y = kx; i = gb * 256 + tid; }
    else if (gb < NKXB + NQXB)  { x = query;   y = qx; i = (gb - NKXB) * 256 + tid; }
    else {
        const int w = gb - NKXB - NQXB;      // 0..1023
        const int which = w >> 8;
        i = (w & 255) * 256 + tid;
        x = (which == 0) ? Wk_m : (which == 1) ? Wk_c : (which == 2) ? Wq_m : Wq_c;
        y = (which == 0) ? kwm  : (which == 1) ? kwc  : (which == 2) ? qwm  : qwc;
    }
    float4 v = ((const float4*)x)[i];
    ushort4 o;
    o.x = f2bf(v.x); o.y = f2bf(v.y); o.z = f2bf(v.z); o.w = f2bf(v.w);
    ((ushort4*)y)[i] = o;
}

// ---------------------------------------------------------------------------
// Staged NT MFMA core (runtime ksteps): 128x128 f32 tile of A[M,K] @ B[N,K]^T.
// 256 threads / 4 waves, each wave a 64x64 subtile.
// ---------------------------------------------------------------------------
__device__ __forceinline__ void mfma_nt_staged(
    const unsigned short* __restrict__ A, const unsigned short* __restrict__ B,
    int lda, int ldb, int bm, int bn,
    unsigned short* AsLDS, unsigned short* BsLDS, f32x4 acc[4][4], int ksteps)
{
    const int t = threadIdx.x;
    const int wv = t >> 6, ln = t & 63;
    const int r = ln & 15, quad = ln >> 4;
    const int wm = (wv >> 1) * 64, wn = (wv & 1) * 64;
    const int srow = wv * 16 + (ln >> 2);
    const int scol = (ln & 3) * 8;

    for (int ks = 0; ks < ksteps; ++ks) {
        const int k0 = ks * 32;
        #pragma unroll
        for (int j = 0; j < 2; ++j) {
            gload_lds16(A + (size_t)(bm + j * 64 + srow) * lda + k0 + scol,
                        AsLDS + (size_t)(j * 64 + wv * 16) * 32);
            gload_lds16(B + (size_t)(bn + j * 64 + srow) * ldb + k0 + scol,
                        BsLDS + (size_t)(j * 64 + wv * 16) * 32);
        }
        __syncthreads();
        bf16x8 af[4], bg[4];
        #pragma unroll
        for (int f = 0; f < 4; ++f)
            af[f] = *(const bf16x8*)(AsLDS + (size_t)(wm + f * 16 + r) * 32 + quad * 8);
        #pragma unroll
        for (int f = 0; f < 4; ++f)
            bg[f] = *(const bf16x8*)(BsLDS + (size_t)(wn + f * 16 + r) * 32 + quad * 8);
        #pragma unroll
        for (int i = 0; i < 4; ++i)
            #pragma unroll
            for (int j2 = 0; j2 < 4; ++j2)
                acc[i][j2] = __builtin_amdgcn_mfma_f32_16x16x32_bf16(
                    af[i], bg[j2], acc[i][j2], 0, 0, 0);
        __syncthreads();
    }
}

__device__ __forceinline__ void zero_acc(f32x4 acc[4][4]) {
    #pragma unroll
    for (int i = 0; i < 4; ++i)
        #pragma unroll
        for (int j = 0; j < 4; ++j)
            acc[i][j] = f32x4{0.f, 0.f, 0.f, 0.f};
}

// ---------------------------------------------------------------------------
// smallg: GT[2560][512] bf16 where GT[n][d]:
//   seg 0 (n<512)      : sum_a Wk_m[n,a] Wq_m[d,a]            (K=512)
//   seg 1+h (rows 512+h*512) : sum_{a in head h} Wk_c[n,a] Wq_c[d,a]  (K=128)
// Also aux: wv[n] (n<2560): bias-fold vectors (Wk@bq per segment);
//           wu[d] = Wq_m@bk_m at aux[2560..3072); cc = bq_m.bk_m at aux[3072].
// ---------------------------------------------------------------------------
__global__ __launch_bounds__(256) void smallg(
    const unsigned short* __restrict__ kwm, const unsigned short* __restrict__ kwc,
    const unsigned short* __restrict__ qwm, const unsigned short* __restrict__ qwc,
    const float* __restrict__ Wk_mf, const float* __restrict__ Wk_cf,
    const float* __restrict__ Wq_mf,
    const float* __restrict__ bq_m, const float* __restrict__ bk_m,
    const float* __restrict__ bq_c,
    unsigned short* __restrict__ GT, float* __restrict__ aux)
{
    __shared__ unsigned short As[128 * 32];
    __shared__ unsigned short Bs[128 * 32];
    __shared__ float red[256];
    const int blk = blockIdx.x, tid = threadIdx.x;

    if (blk < 80) {
        const int seg = blk >> 4, t = blk & 15;
        const int bm = (t >> 2) * 128, bn = (t & 3) * 128;
        const unsigned short *A, *B; int ks;
        if (seg == 0) { A = kwm; B = qwm; ks = 16; }
        else { const int h = seg - 1; A = kwc + h * 128; B = qwc + h * 128; ks = 4; }
        f32x4 acc[4][4]; zero_acc(acc);
        mfma_nt_staged(A, B, 512, 512, bm, bn, As, Bs, acc, ks);
        const int wv = tid >> 6, ln = tid & 63;
        const int r = ln & 15, quad = ln >> 4;
        const int m0 = bm + (wv >> 1) * 64, n0 = bn + (wv & 1) * 64;
        #pragma unroll
        for (int j = 0; j < 4; ++j) {
            const int n = n0 + j * 16 + r;
            #pragma unroll
            for (int i = 0; i < 4; ++i)
                #pragma unroll
                for (int reg = 0; reg < 4; ++reg) {
                    const int m = m0 + i * 16 + quad * 4 + reg;
                    GT[(size_t)(seg * 512 + m) * 512 + n] = f2bf(acc[i][j][reg]);
                }
        }
        return;
    }
    const int ab = blk - 80;
    if (ab < 2) {                       // mono wv: Wk_m @ bq_m
        const int d = ab * 256 + tid;
        const float* row = Wk_mf + (size_t)d * 512;
        float s = 0.f;
        for (int j = 0; j < 512; j += 4) {
            float4 a = *(const float4*)(row + j);
            float4 b = *(const float4*)(bq_m + j);
            s += a.x * b.x + a.y * b.y + a.z * b.z + a.w * b.w;
        }
        aux[d] = s; return;
    }
    if (ab < 10) {                      // head wv: Wk_c[:,h-slice] @ bq_c[h-slice]
        const int t = ab - 2, h = t >> 1;
        const int d = (t & 1) * 256 + tid;
        const float* row = Wk_cf + (size_t)d * 512 + h * 128;
        const float* bv = bq_c + h * 128;
        float s = 0.f;
        for (int j = 0; j < 128; j += 4) {
            float4 a = *(const float4*)(row + j);
            float4 b = *(const float4*)(bv + j);
            s += a.x * b.x + a.y * b.y + a.z * b.z + a.w * b.w;
        }
        aux[512 + h * 512 + d] = s; return;
    }
    if (ab < 12) {                      // wu: Wq_m @ bk_m
        const int d = (ab - 10) * 256 + tid;
        const float* row = Wq_mf + (size_t)d * 512;
        float s = 0.f;
        for (int j = 0; j < 512; j += 4) {
            float4 a = *(const float4*)(row + j);
            float4 b = *(const float4*)(bk_m + j);
            s += a.x * b.x + a.y * b.y + a.z * b.z + a.w * b.w;
        }
        aux[GCOLS + d] = s; return;
    }
    // cc = dot(bq_m, bk_m)
    float s = bq_m[tid] * bk_m[tid] + bq_m[tid + 256] * bk_m[tid + 256];
    red[tid] = s; __syncthreads();
    for (int o = 128; o > 0; o >>= 1) {
        if (tid < o) red[tid] += red[tid + o];
        __syncthreads();
    }
    if (tid == 0) aux[GCOLS + 512] = red[0];
}

// ---------------------------------------------------------------------------
// qg_kernel: qg[2048][2560] bf16 = qx @ GT^T + wv  (NT, K=512).
// Blocks 0..319: 128x128 tiles. Blocks 320..327: vq2[q] = (qx[q].wu + cc)/scale.
// ---------------------------------------------------------------------------
__global__ __launch_bounds__(256) void qg_kernel(
    const unsigned short* __restrict__ qx, const unsigned short* __restrict__ GT,
    const float* __restrict__ aux,
    unsigned short* __restrict__ qg, float* __restrict__ vq2)
{
    __shared__ unsigned short As[128 * 32];
    __shared__ unsigned short Bs[128 * 32];
    __shared__ float wuS[512];
    const int v = blockIdx.x, tid = threadIdx.x;
    if (v < 320) {
        const int by = v / 20, bx = v % 20;
        const int bm = by * 128, bn = bx * 128;
        f32x4 acc[4][4]; zero_acc(acc);
        mfma_nt_staged(qx, GT, 512, 512, bm, bn, As, Bs, acc, 16);
        const int wv = tid >> 6, ln = tid & 63;
        const int r = ln & 15, quad = ln >> 4;
        const int m0 = bm + (wv >> 1) * 64, n0 = bn + (wv & 1) * 64;
        #pragma unroll
        for (int j = 0; j < 4; ++j) {
            const int n = n0 + j * 16 + r;
            const float wvb = aux[n];
            #pragma unroll
            for (int i = 0; i < 4; ++i)
                #pragma unroll
                for (int reg = 0; reg < 4; ++reg) {
                    const int m = m0 + i * 16 + quad * 4 + reg;
                    qg[(size_t)m * GCOLS + n] = f2bf(acc[i][j][reg] + wvb);
                }
        }
        return;
    }
    // vq2
    wuS[tid] = aux[GCOLS + tid];
    wuS[tid + 256] = aux[GCOLS + tid + 256];
    __syncthreads();
    const float cc = aux[GCOLS + 512];
    const int q = (v - 320) * 256 + tid;
    const unsigned short* row = qx + (size_t)q * 512;
    float s = 0.f;
    for (int j = 0; j < 512; j += 4) {
        ushort4 a = *(const ushort4*)(row + j);
        s = fmaf(bf2f(a.x), wuS[j], s);
        s = fmaf(bf2f(a.y), wuS[j + 1], s);
        s = fmaf(bf2f(a.z), wuS[j + 2], s);
        s = fmaf(bf2f(a.w), wuS[j + 3], s);
    }
    vq2[q] = (s + cc) * INV_SCALE;
}

// ---------------------------------------------------------------------------
// p_choose: p = sigmoid(qg_mono[b] @ kx[b]^T / scale + vq2 + r + noise)
// ---------------------------------------------------------------------------
__global__ __launch_bounds__(256) void pchoose_mfma(
    const unsigned short* __restrict__ qg, const unsigned short* __restrict__ kx,
    const float* __restrict__ noise, const float* __restrict__ rp,
    const float* __restrict__ vq2, float* __restrict__ p)
{
    __shared__ unsigned short As[128 * 32];
    __shared__ unsigned short Bs[128 * 32];
    const int b = blockIdx.z;
    const unsigned short* A = qg + (size_t)b * QLEN * GCOLS;      // mono cols 0..512
    const unsigned short* B = kx + (size_t)b * KLEN * 512;
    const int bm = blockIdx.y * 128, bn = blockIdx.x * 128;
    f32x4 acc[4][4]; zero_acc(acc);
    mfma_nt_staged(A, B, GCOLS, 512, bm, bn, As, Bs, acc, 16);
    const int wv = threadIdx.x >> 6, ln = threadIdx.x & 63;
    const int r = ln & 15, quad = ln >> 4;
    const int m0 = bm + (wv >> 1) * 64, n0 = bn + (wv & 1) * 64;
    const float rv = rp[0];
    #pragma unroll
    for (int i = 0; i < 4; ++i) {
        #pragma unroll
        for (int reg = 0; reg < 4; ++reg) {
            const int q = m0 + i * 16 + quad * 4 + reg;
            const size_t rowoff = ((size_t)b * QLEN + q) * KLEN;
            const float vq = vq2[b * QLEN + q] + rv;
            #pragma unroll
            for (int j = 0; j < 4; ++j) {
                const int k = n0 + j * 16 + r;
                const float e = acc[i][j][reg] * INV_SCALE + vq + noise[rowoff + k];
                p[rowoff + k] = __builtin_amdgcn_rcpf(1.0f + __expf(-e));
            }
        }
    }
}

// ---------------------------------------------------------------------------
// 64-lane inclusive prefix sum via DPP (≈6 VALU ops)
// ---------------------------------------------------------------------------
__device__ __forceinline__ float wave_incl_scan(float x)
{
#define DPP_ADD(ctrl, rmask, bctrl)                                            \
    { int _t = __builtin_amdgcn_update_dpp(0, __builtin_bit_cast(int, x),      \
                                           ctrl, rmask, 0xf, bctrl);           \
      x += __builtin_bit_cast(float, _t); }
    DPP_ADD(0x111, 0xf, true)   // row_shr:1
    DPP_ADD(0x112, 0xf, true)   // row_shr:2
    DPP_ADD(0x114, 0xf, true)   // row_shr:4
    DPP_ADD(0x118, 0xf, true)   // row_shr:8
    DPP_ADD(0x142, 0xa, false)  // row_bcast:15 -> rows 1,3
    DPP_ADD(0x143, 0xc, false)  // row_bcast:31 -> rows 2,3
#undef DPP_ADD
    return x;
}

// ---------------------------------------------------------------------------
// cumprod_mr: per (b,q) row: cp = exp(excl_cumsum(log(clip(1-p)))); emits
// m = p*cp, r = 1/clip(cp).
// ---------------------------------------------------------------------------
__global__ __launch_bounds__(256) void cumprod_mr(
    const float* __restrict__ p, float* __restrict__ mArr, float* __restrict__ rArr)
{
    const size_t row = blockIdx.x;
    const float* pr = p + row * KLEN;
    float* mr = mArr + row * KLEN;
    float* rr = rArr + row * KLEN;
    const int tid = threadIdx.x;
    const int lane = tid & 63, wid = tid >> 6;
    __shared__ float waveTot[4];

    float4 v0 = *(const float4*)(pr + tid * 8);
    float4 v1 = *(const float4*)(pr + tid * 8 + 4);
    float pv[8] = {v0.x, v0.y, v0.z, v0.w, v1.x, v1.y, v1.z, v1.w};
    float excl[8];
    float run = 0.0f;
    #pragma unroll
    for (int j = 0; j < 8; ++j) {
        float l = __logf(fminf(fmaxf(1.0f - pv[j], EPSV), 1.0f));
        excl[j] = run;
        run += l;
    }
    float s = wave_incl_scan(run);
    if (lane == 63) waveTot[wid] = s;
    __syncthreads();
    float wex = 0.0f;
    for (int w = 0; w < wid; ++w) wex += waveTot[w];
    const float texcl = wex + s - run;

    float mv[8], rv[8];
    #pragma unroll
    for (int j = 0; j < 8; ++j) {
        const float cpv = __expf(texcl + excl[j]);
        mv[j] = pv[j] * cpv;
        rv[j] = __builtin_amdgcn_rcpf(fminf(fmaxf(cpv, EPSV), 1.0f));
    }
    *(float4*)(mr + tid * 8)     = *(float4*)&mv[0];
    *(float4*)(mr + tid * 8 + 4) = *(float4*)&mv[4];
    *(float4*)(rr + tid * 8)     = *(float4*)&rv[0];
    *(float4*)(rr + tid * 8 + 4) = *(float4*)&rv[4];
}

// ---------------------------------------------------------------------------
// alpha_echunk: FUSED kernel, 512 threads.
//  Blocks 0..7: alpha recurrence — EXACT R3 form (85.8 us, best of 5 tested
//    structures; R2/R4/R5/R6 alternatives all lost). 8 waves, barrier/step.
//  Blocks 8..519: e_chunk via G-matrices: e[b,h] = qg_h[b] @ kx[b]^T (K=512).
//    8-wave 128x256 tiles (all 512 threads work now). 512 blocks x 33.5 MF
//    run under alpha's shadow on the other ~248 CUs.
//  smem 96 KB -> 1 block/CU isolation for alpha (+4% proven, kept).
// ---------------------------------------------------------------------------
__global__ __launch_bounds__(512, 1) void alpha_echunk(
    const float* __restrict__ mArr, const float* __restrict__ rArr,
    float* __restrict__ alpha,
    const unsigned short* __restrict__ qg, const unsigned short* __restrict__ kx,
    float* __restrict__ out)
{
    __shared__ __align__(16) char smem[98304];   // 96 KB -> 1 block/CU
    const int bid = blockIdx.x;
    const int tid = threadIdx.x;

    if (bid < BATCH) {
        // ---------------- alpha scan (R3 structure, proven) ----------------
        __builtin_amdgcn_s_setprio(1);
        float (*wt)[8] = (float (*)[8])smem;   // [2][8]
        const int lane = tid & 63, wid = tid >> 6;
        const float* mrow = mArr + (size_t)bid * QLEN * KLEN + tid * 4;
        const float* rrow = rArr + (size_t)bid * QLEN * KLEN + tid * 4;
        float* arow = alpha + (size_t)bid * QLEN * KLEN + tid * 4;

        float aw0 = 0.f, aw1 = 0.f, aw2 = 0.f, aw3 = 0.f;
        if (tid == 0) aw0 = 1.0f;   // aw_prev one-hot at k=0

        float4 mA = *(const float4*)(mrow);
        float4 rA = *(const float4*)(rrow);
        float4 mB = *(const float4*)(mrow + KLEN);
        float4 rB = *(const float4*)(rrow + KLEN);

#define ASTEP(I, MREG, RREG)                                                   \
    {                                                                          \
        const int i_ = (I);                                                    \
        float4 mc = MREG, rc = RREG;                                           \
        const int rn_ = (i_ + 2 < QLEN) ? (i_ + 2) : (QLEN - 1);               \
        MREG = *(const float4*)(mrow + (size_t)rn_ * KLEN);                    \
        RREG = *(const float4*)(rrow + (size_t)rn_ * KLEN);                    \
        float run = 0.0f, i0, i1, i2, i3;                                      \
        run = fmaf(aw0, rc.x, run); i0 = run;                                  \
        run = fmaf(aw1, rc.y, run); i1 = run;                                  \
        run = fmaf(aw2, rc.z, run); i2 = run;                                  \
        run = fmaf(aw3, rc.w, run); i3 = run;                                  \
        float tot = wave_incl_scan(run);                                       \
        if (lane == 63) wt[i_ & 1][wid] = tot;                                 \
        lds_barrier();                                                         \
        float base = tot - run;                                                \
        float4 w0 = *(const float4*)&wt[i_ & 1][0];                            \
        float4 w1 = *(const float4*)&wt[i_ & 1][4];                            \
        if (wid > 0) base += w0.x;                                             \
        if (wid > 1) base += w0.y;                                             \
        if (wid > 2) base += w0.z;                                             \
        if (wid > 3) base += w0.w;                                             \
        if (wid > 4) base += w1.x;                                             \
        if (wid > 5) base += w1.y;                                             \
        if (wid > 6) base += w1.z;                                             \
        aw0 = mc.x * (base + i0);                                              \
        aw1 = mc.y * (base + i1);                                              \
        aw2 = mc.z * (base + i2);                                              \
        aw3 = mc.w * (base + i3);                                              \
        float4 ov; ov.x = aw0; ov.y = aw1; ov.z = aw2; ov.w = aw3;             \
        *(float4*)(arow + (size_t)i_ * KLEN) = ov;                             \
    }

        for (int io = 0; io < QLEN; io += 2) {
            ASTEP(io + 0, mA, rA)
            ASTEP(io + 1, mB, rB)
        }
#undef ASTEP
        __builtin_amdgcn_s_setprio(0);
        return;
    }

    // -------- echunk tile: 8 waves, 128x256, K=512 --------
    const int v = bid - BATCH;           // 0..511
    const int z = v >> 4;                // 0..31 = b*4+h
    const int rest = v & 15;
    const int by = rest >> 3;            // 0..1
    const int bx = rest & 7;             // 0..7
    const int b = z >> 2, h = z & 3;
    unsigned short* As = (unsigned short*)smem;             // 8 KB (128x32)
    unsigned short* Bs = (unsigned short*)(smem + 8192);    // 16 KB (256x32)
    const unsigned short* A = qg + (size_t)(b * QLEN) * GCOLS + 512 + h * 512;
    const unsigned short* B = kx + (size_t)b * KLEN * 512;
    const int bm = by * 128, bn = bx * 256;

    const int wv8 = tid >> 6, ln = tid & 63;
    const int r = ln & 15, quad = ln >> 4;
    const int wr = wv8 >> 2, wc = wv8 & 3;
    const int srow = tid >> 2;           // 0..127
    const int scol = (ln & 3) * 8;

    f32x4 acc[4][4]; zero_acc(acc);
    for (int ks = 0; ks < 16; ++ks) {
        const int k0 = ks * 32;
        // j=0: A rows; j=1: B rows 0..127; j=2: B rows 128..255
        gload_lds16(A + (size_t)(bm + srow) * GCOLS + k0 + scol,
                    As + (size_t)wv8 * 512);
        gload_lds16(B + (size_t)(bn + srow) * 512 + k0 + scol,
                    Bs + (size_t)wv8 * 512);
        gload_lds16(B + (size_t)(bn + 128 + srow) * 512 + k0 + scol,
                    Bs + 4096 + (size_t)wv8 * 512);
        __syncthreads();
        bf16x8 af[4], bg[4];
        #pragma unroll
        for (int f = 0; f < 4; ++f)
            af[f] = *(const bf16x8*)(As + (size_t)(wr * 64 + f * 16 + r) * 32 + quad * 8);
        #pragma unroll
        for (int f = 0; f < 4; ++f)
            bg[f] = *(const bf16x8*)(Bs + (size_t)(wc * 64 + f * 16 + r) * 32 + quad * 8);
        #pragma unroll
        for (int i = 0; i < 4; ++i)
            #pragma unroll
            for (int j2 = 0; j2 < 4; ++j2)
                acc[i][j2] = __builtin_amdgcn_mfma_f32_16x16x32_bf16(
                    af[i], bg[j2], acc[i][j2], 0, 0, 0);
        __syncthreads();
    }
    {
        const int m0 = bm + wr * 64, n0 = bn + wc * 64;
        #pragma unroll
        for (int i = 0; i < 4; ++i) {
            #pragma unroll
            for (int reg = 0; reg < 4; ++reg) {
                const int q = m0 + i * 16 + quad * 4 + reg;
                const size_t rowoff = ((size_t)z * QLEN + q) * KLEN;
                #pragma unroll
                for (int j = 0; j < 4; ++j) {
                    const int k = n0 + j * 16 + r;
                    out[rowoff + k] = acc[i][j][reg] * INV_SCALE;
                }
            }
        }
    }
}

// ---------------------------------------------------------------------------
// beta: per (b,h,q) row of 2048 (e_chunk in d_out, overwritten)
// ---------------------------------------------------------------------------
__global__ __launch_bounds__(256) void beta_kernel(
    float* __restrict__ eo, const float* __restrict__ alpha)
{
    __shared__ float sse[KLEN + 3];
    __shared__ float su[KLEN + 3];
    __shared__ float wmax[4];

    const int tid = threadIdx.x;
    const int lane = tid & 63, wid = tid >> 6;
    const int row = blockIdx.x;                 // [B*H*Q]
    const int q = row & (QLEN - 1);
    const int b = row >> 10;
    float* erow = eo + (size_t)row * KLEN;
    const float* arow = alpha + ((size_t)b * QLEN + q) * KLEN;

    if (tid < 3) { sse[tid] = 0.0f; su[KLEN + tid] = 0.0f; }

    float ev[8];
    float lm = -INFINITY;
    #pragma unroll
    for (int j = 0; j < 8; ++j) {
        const int k = tid + 256 * j;
        ev[j] = erow[k];
        lm = fmaxf(lm, ev[j]);
    }
    #pragma unroll
    for (int off = 32; off > 0; off >>= 1) lm = fmaxf(lm, __shfl_xor(lm, off));
    if (lane == 0) wmax[wid] = lm;
    __syncthreads();
    const float mx = fmaxf(fmaxf(wmax[0], wmax[1]), fmaxf(wmax[2], wmax[3]));

    #pragma unroll
    for (int j = 0; j < 8; ++j) {
        const int k = tid + 256 * j;
        sse[k + 3] = fmaxf(__expf(ev[j] - mx), 1e-5f);
    }
    __syncthreads();

    #pragma unroll
    for (int j = 0; j < 8; ++j) {
        const int k = tid + 256 * j;
        const float denom = sse[k + 3] + sse[k + 2] + sse[k + 1] + sse[k];
        su[k] = arow[k] * __builtin_amdgcn_rcpf(denom);
    }
    __syncthreads();

    #pragma unroll
    for (int j = 0; j < 8; ++j) {
        const int k = tid + 256 * j;
        erow[k] = sse[k + 3] * (su[k] + su[k + 1] + su[k + 2] + su[k + 3]);
    }
}

// ---------------------------------------------------------------------------
extern "C" void kernel_launch(void* const* d_in, const int* in_sizes, int n_in,
                              void* d_out, int out_size, void* d_ws, size_t ws_size,
                              hipStream_t stream)
{
    (void)in_sizes; (void)n_in; (void)out_size; (void)ws_size;
    const float* key_enc = (const float*)d_in[0];   // [8,2048,512]
    const float* query   = (const float*)d_in[1];   // [8,256,512]
    const float* noise   = (const float*)d_in[2];   // [8,256,2048]
    const float* Wk_m    = (const float*)d_in[3];
    const float* bk_m    = (const float*)d_in[4];
    const float* Wq_m    = (const float*)d_in[5];
    const float* bq_m    = (const float*)d_in[6];
    const float* rp      = (const float*)d_in[7];
    const float* Wk_c    = (const float*)d_in[8];
    const float* bk_c    = (const float*)d_in[9];
    const float* Wq_c    = (const float*)d_in[10];
    const float* bq_c    = (const float*)d_in[11];
    float* out = (float*)d_out;                     // [8,4,256,2048]
    (void)bk_c;

    // workspace layout (bytes)
    char* w = (char*)d_ws;
    unsigned short* kx   = (unsigned short*)w; w += (size_t)BATCH * KLEN * KDIM * 2;  // 16.8 MB
    unsigned short* qx   = (unsigned short*)w; w += (size_t)QROWS * KDIM * 2;         //  2.1 MB
    unsigned short* kwm  = (unsigned short*)w; w += (size_t)512 * 512 * 2;
    unsigned short* kwc  = (unsigned short*)w; w += (size_t)512 * 512 * 2;
    unsigned short* qwm  = (unsigned short*)w; w += (size_t)512 * 512 * 2;
    unsigned short* qwc  = (unsigned short*)w; w += (size_t)512 * 512 * 2;
    unsigned short* GT   = (unsigned short*)w; w += (size_t)GCOLS * 512 * 2;          //  2.6 MB
    unsigned short* qg   = (unsigned short*)w; w += (size_t)QROWS * GCOLS * 2;        // 10.5 MB
    float* aux    = (float*)w; w += 4096 * 4;
    float* vq2    = (float*)w; w += QROWS * 4;
    float* p_alpha = (float*)w; w += (size_t)BATCH * QLEN * KLEN * 4;                 // 16.8 MB
    float* mArr    = (float*)w; w += (size_t)BATCH * QLEN * KLEN * 4;                 // 16.8 MB
    float* rArr    = (float*)w;                                                       // 16.8 MB

    // 1) casts (inputs + weights)
    hipLaunchKernelGGL(prep, dim3(NKXB + NQXB + 1024), dim3(256), 0, stream,
                       key_enc, query, Wk_m, Wk_c, Wq_m, Wq_c,
                       kx, qx, kwm, kwc, qwm, qwc);

    // 2) G matrices + bias-fold vectors (tiny)
    hipLaunchKernelGGL(smallg, dim3(93), dim3(256), 0, stream,
                       kwm, kwc, qwm, qwc, Wk_m, Wk_c, Wq_m,
                       bq_m, bk_m, bq_c, GT, aux);

    // 3) qg = qx @ GT^T + wv  (+ vq2)
    hipLaunchKernelGGL(qg_kernel, dim3(328), dim3(256), 0, stream,
                       qx, GT, aux, qg, vq2);

    // 4) p_choose
    hipLaunchKernelGGL(pchoose_mfma, dim3(KLEN / 128, QLEN / 128, BATCH), dim3(256), 0, stream,
                       qg, kx, noise, rp, vq2, p_alpha);

    // 5) cumprod -> (m, r)
    hipLaunchKernelGGL(cumprod_mr, dim3(BATCH * QLEN), dim3(256), 0, stream,
                       p_alpha, mArr, rArr);

    // 6) FUSED: alpha recurrence (blocks 0..7) + e_chunk (blocks 8..519)
    hipLaunchKernelGGL(alpha_echunk, dim3(BATCH + 512), dim3(512), 0, stream,
                       mArr, rArr, p_alpha, qg, kx, out);

    // 7) beta (overwrites e_chunk rows in d_out)
    hipLaunchKernelGGL(beta_kernel, dim3(BATCH * NHEADS * QLEN), dim3(256), 0, stream,
                       out, p_alpha);
}

// Round 8
// 279.175 us; speedup vs baseline: 1.1021x; 1.0135x over previous
//
#include <hip/hip_runtime.h>
#include <math.h>

// Problem constants
#define BATCH   8
#define QLEN    256
#define KLEN    2048
#define KDIM    512
#define NHEADS  4
#define DKH     128
#define NG      5                       // mono + 4 heads
#define QROWS   (BATCH * QLEN)          // 2048
#define GCOLS   (NG * 512)              // 2560

static constexpr float INV_SCALE = 0.04419417382415922f; // 1/sqrt(512)
static constexpr float EPSV = 1e-6f;

typedef __attribute__((ext_vector_type(8))) short bf16x8;
typedef __attribute__((ext_vector_type(4))) float f32x4;

__device__ __forceinline__ unsigned short f2bf(float f) {
    unsigned u = __builtin_bit_cast(unsigned, f);
    u += 0x7fffu + ((u >> 16) & 1u);   // round-to-nearest-even
    return (unsigned short)(u >> 16);
}
__device__ __forceinline__ float bf2f(unsigned short u) {
    unsigned x = (unsigned)u << 16;
    return __builtin_bit_cast(float, x);
}

// Barrier waiting only on LDS ops (lgkmcnt); global loads/stores stay in flight.
__device__ __forceinline__ void lds_barrier() {
    __asm__ volatile("s_waitcnt lgkmcnt(0)\n\ts_barrier" ::: "memory");
}

// Async global->LDS, 16 B per lane (wave-uniform base + lane*16 rule).
__device__ __forceinline__ void gload_lds16(const void* g, void* l) {
    __builtin_amdgcn_global_load_lds(
        (const __attribute__((address_space(1))) void*)g,
        (__attribute__((address_space(3))) void*)l, 16, 0, 0);
}

// ---------------------------------------------------------------------------
// prep: all f32->bf16 casts in one launch.
// ---------------------------------------------------------------------------
#define NKXB 8192
#define NQXB 1024
__global__ __launch_bounds__(256) void prep(
    const float* __restrict__ key_enc, const float* __restrict__ query,
    const float* __restrict__ Wk_m, const float* __restrict__ Wk_c,
    const float* __restrict__ Wq_m, const float* __restrict__ Wq_c,
    unsigned short* __restrict__ kx, unsigned short* __restrict__ qx,
    unsigned short* __restrict__ kwm, unsigned short* __restrict__ kwc,
    unsigned short* __restrict__ qwm, unsigned short* __restrict__ qwc)
{
    const int gb = blockIdx.x, tid = threadIdx.x;
    const float* x; unsigned short* y; int i;
    if (gb < NKXB)              { x = key_enc; y = kx; i = gb * 256 + tid; }
    else if (gb < NKXB + NQXB)  { x = query;   y = qx; i = (gb - NKXB) * 256 + tid; }
    else {
        const int w = gb - NKXB - NQXB;      // 0..1023
        const int which = w >> 8;
        i = (w & 255) * 256 + tid;
        x = (which == 0) ? Wk_m : (which == 1) ? Wk_c : (which == 2) ? Wq_m : Wq_c;
        y = (which == 0) ? kwm  : (which == 1) ? kwc  : (which == 2) ? qwm  : qwc;
    }
    float4 v = ((const float4*)x)[i];
    ushort4 o;
    o.x = f2bf(v.x); o.y = f2bf(v.y); o.z = f2bf(v.z); o.w = f2bf(v.w);
    ((ushort4*)y)[i] = o;
}

// ---------------------------------------------------------------------------
// Staged NT MFMA core (runtime ksteps): 128x128 f32 tile of A[M,K] @ B[N,K]^T.
// 256 threads / 4 waves, each wave a 64x64 subtile.
// ---------------------------------------------------------------------------
__device__ __forceinline__ void mfma_nt_staged(
    const unsigned short* __restrict__ A, const unsigned short* __restrict__ B,
    int lda, int ldb, int bm, int bn,
    unsigned short* AsLDS, unsigned short* BsLDS, f32x4 acc[4][4], int ksteps)
{
    const int t = threadIdx.x;
    const int wv = t >> 6, ln = t & 63;
    const int r = ln & 15, quad = ln >> 4;
    const int wm = (wv >> 1) * 64, wn = (wv & 1) * 64;
    const int srow = wv * 16 + (ln >> 2);
    const int scol = (ln & 3) * 8;

    for (int ks = 0; ks < ksteps; ++ks) {
        const int k0 = ks * 32;
        #pragma unroll
        for (int j = 0; j < 2; ++j) {
            gload_lds16(A + (size_t)(bm + j * 64 + srow) * lda + k0 + scol,
                        AsLDS + (size_t)(j * 64 + wv * 16) * 32);
            gload_lds16(B + (size_t)(bn + j * 64 + srow) * ldb + k0 + scol,
                        BsLDS + (size_t)(j * 64 + wv * 16) * 32);
        }
        __syncthreads();
        bf16x8 af[4], bg[4];
        #pragma unroll
        for (int f = 0; f < 4; ++f)
            af[f] = *(const bf16x8*)(AsLDS + (size_t)(wm + f * 16 + r) * 32 + quad * 8);
        #pragma unroll
        for (int f = 0; f < 4; ++f)
            bg[f] = *(const bf16x8*)(BsLDS + (size_t)(wn + f * 16 + r) * 32 + quad * 8);
        #pragma unroll
        for (int i = 0; i < 4; ++i)
            #pragma unroll
            for (int j2 = 0; j2 < 4; ++j2)
                acc[i][j2] = __builtin_amdgcn_mfma_f32_16x16x32_bf16(
                    af[i], bg[j2], acc[i][j2], 0, 0, 0);
        __syncthreads();
    }
}

__device__ __forceinline__ void zero_acc(f32x4 acc[4][4]) {
    #pragma unroll
    for (int i = 0; i < 4; ++i)
        #pragma unroll
        for (int j = 0; j < 4; ++j)
            acc[i][j] = f32x4{0.f, 0.f, 0.f, 0.f};
}

// ---------------------------------------------------------------------------
// smallg: GT[2560][512] bf16 (G matrices) + bias-fold vectors in aux.
// ---------------------------------------------------------------------------
__global__ __launch_bounds__(256) void smallg(
    const unsigned short* __restrict__ kwm, const unsigned short* __restrict__ kwc,
    const unsigned short* __restrict__ qwm, const unsigned short* __restrict__ qwc,
    const float* __restrict__ Wk_mf, const float* __restrict__ Wk_cf,
    const float* __restrict__ Wq_mf,
    const float* __restrict__ bq_m, const float* __restrict__ bk_m,
    const float* __restrict__ bq_c,
    unsigned short* __restrict__ GT, float* __restrict__ aux)
{
    __shared__ unsigned short As[128 * 32];
    __shared__ unsigned short Bs[128 * 32];
    __shared__ float red[256];
    const int blk = blockIdx.x, tid = threadIdx.x;

    if (blk < 80) {
        const int seg = blk >> 4, t = blk & 15;
        const int bm = (t >> 2) * 128, bn = (t & 3) * 128;
        const unsigned short *A, *B; int ks;
        if (seg == 0) { A = kwm; B = qwm; ks = 16; }
        else { const int h = seg - 1; A = kwc + h * 128; B = qwc + h * 128; ks = 4; }
        f32x4 acc[4][4]; zero_acc(acc);
        mfma_nt_staged(A, B, 512, 512, bm, bn, As, Bs, acc, ks);
        const int wv = tid >> 6, ln = tid & 63;
        const int r = ln & 15, quad = ln >> 4;
        const int m0 = bm + (wv >> 1) * 64, n0 = bn + (wv & 1) * 64;
        #pragma unroll
        for (int j = 0; j < 4; ++j) {
            const int n = n0 + j * 16 + r;
            #pragma unroll
            for (int i = 0; i < 4; ++i)
                #pragma unroll
                for (int reg = 0; reg < 4; ++reg) {
                    const int m = m0 + i * 16 + quad * 4 + reg;
                    GT[(size_t)(seg * 512 + m) * 512 + n] = f2bf(acc[i][j][reg]);
                }
        }
        return;
    }
    const int ab = blk - 80;
    if (ab < 2) {                       // mono wv: Wk_m @ bq_m
        const int d = ab * 256 + tid;
        const float* row = Wk_mf + (size_t)d * 512;
        float s = 0.f;
        for (int j = 0; j < 512; j += 4) {
            float4 a = *(const float4*)(row + j);
            float4 b = *(const float4*)(bq_m + j);
            s += a.x * b.x + a.y * b.y + a.z * b.z + a.w * b.w;
        }
        aux[d] = s; return;
    }
    if (ab < 10) {                      // head wv: Wk_c[:,h-slice] @ bq_c[h-slice]
        const int t = ab - 2, h = t >> 1;
        const int d = (t & 1) * 256 + tid;
        const float* row = Wk_cf + (size_t)d * 512 + h * 128;
        const float* bv = bq_c + h * 128;
        float s = 0.f;
        for (int j = 0; j < 128; j += 4) {
            float4 a = *(const float4*)(row + j);
            float4 b = *(const float4*)(bv + j);
            s += a.x * b.x + a.y * b.y + a.z * b.z + a.w * b.w;
        }
        aux[512 + h * 512 + d] = s; return;
    }
    if (ab < 12) {                      // wu: Wq_m @ bk_m
        const int d = (ab - 10) * 256 + tid;
        const float* row = Wq_mf + (size_t)d * 512;
        float s = 0.f;
        for (int j = 0; j < 512; j += 4) {
            float4 a = *(const float4*)(row + j);
            float4 b = *(const float4*)(bk_m + j);
            s += a.x * b.x + a.y * b.y + a.z * b.z + a.w * b.w;
        }
        aux[GCOLS + d] = s; return;
    }
    // cc = dot(bq_m, bk_m)
    float s = bq_m[tid] * bk_m[tid] + bq_m[tid + 256] * bk_m[tid + 256];
    red[tid] = s; __syncthreads();
    for (int o = 128; o > 0; o >>= 1) {
        if (tid < o) red[tid] += red[tid + o];
        __syncthreads();
    }
    if (tid == 0) aux[GCOLS + 512] = red[0];
}

// ---------------------------------------------------------------------------
// qg_kernel: qg[2048][2560] bf16 = qx @ GT^T + wv  (NT, K=512).
// Blocks 0..319: 128x128 tiles. Blocks 320..327: vq2[q] = (qx[q].wu + cc)/scale.
// ---------------------------------------------------------------------------
__global__ __launch_bounds__(256) void qg_kernel(
    const unsigned short* __restrict__ qx, const unsigned short* __restrict__ GT,
    const float* __restrict__ aux,
    unsigned short* __restrict__ qg, float* __restrict__ vq2)
{
    __shared__ unsigned short As[128 * 32];
    __shared__ unsigned short Bs[128 * 32];
    __shared__ float wuS[512];
    const int v = blockIdx.x, tid = threadIdx.x;
    if (v < 320) {
        const int by = v / 20, bx = v % 20;
        const int bm = by * 128, bn = bx * 128;
        f32x4 acc[4][4]; zero_acc(acc);
        mfma_nt_staged(qx, GT, 512, 512, bm, bn, As, Bs, acc, 16);
        const int wv = tid >> 6, ln = tid & 63;
        const int r = ln & 15, quad = ln >> 4;
        const int m0 = bm + (wv >> 1) * 64, n0 = bn + (wv & 1) * 64;
        #pragma unroll
        for (int j = 0; j < 4; ++j) {
            const int n = n0 + j * 16 + r;
            const float wvb = aux[n];
            #pragma unroll
            for (int i = 0; i < 4; ++i)
                #pragma unroll
                for (int reg = 0; reg < 4; ++reg) {
                    const int m = m0 + i * 16 + quad * 4 + reg;
                    qg[(size_t)m * GCOLS + n] = f2bf(acc[i][j][reg] + wvb);
                }
        }
        return;
    }
    // vq2
    wuS[tid] = aux[GCOLS + tid];
    wuS[tid + 256] = aux[GCOLS + tid + 256];
    __syncthreads();
    const float cc = aux[GCOLS + 512];
    const int q = (v - 320) * 256 + tid;
    const unsigned short* row = qx + (size_t)q * 512;
    float s = 0.f;
    for (int j = 0; j < 512; j += 4) {
        ushort4 a = *(const ushort4*)(row + j);
        s = fmaf(bf2f(a.x), wuS[j], s);
        s = fmaf(bf2f(a.y), wuS[j + 1], s);
        s = fmaf(bf2f(a.z), wuS[j + 2], s);
        s = fmaf(bf2f(a.w), wuS[j + 3], s);
    }
    vq2[q] = (s + cc) * INV_SCALE;
}

// ---------------------------------------------------------------------------
// p_choose: p = sigmoid(qg_mono[b] @ kx[b]^T / scale + vq2 + r + noise)
// ---------------------------------------------------------------------------
__global__ __launch_bounds__(256) void pchoose_mfma(
    const unsigned short* __restrict__ qg, const unsigned short* __restrict__ kx,
    const float* __restrict__ noise, const float* __restrict__ rp,
    const float* __restrict__ vq2, float* __restrict__ p)
{
    __shared__ unsigned short As[128 * 32];
    __shared__ unsigned short Bs[128 * 32];
    const int b = blockIdx.z;
    const unsigned short* A = qg + (size_t)b * QLEN * GCOLS;      // mono cols 0..512
    const unsigned short* B = kx + (size_t)b * KLEN * 512;
    const int bm = blockIdx.y * 128, bn = blockIdx.x * 128;
    f32x4 acc[4][4]; zero_acc(acc);
    mfma_nt_staged(A, B, GCOLS, 512, bm, bn, As, Bs, acc, 16);
    const int wv = threadIdx.x >> 6, ln = threadIdx.x & 63;
    const int r = ln & 15, quad = ln >> 4;
    const int m0 = bm + (wv >> 1) * 64, n0 = bn + (wv & 1) * 64;
    const float rv = rp[0];
    #pragma unroll
    for (int i = 0; i < 4; ++i) {
        #pragma unroll
        for (int reg = 0; reg < 4; ++reg) {
            const int q = m0 + i * 16 + quad * 4 + reg;
            const size_t rowoff = ((size_t)b * QLEN + q) * KLEN;
            const float vq = vq2[b * QLEN + q] + rv;
            #pragma unroll
            for (int j = 0; j < 4; ++j) {
                const int k = n0 + j * 16 + r;
                const float e = acc[i][j][reg] * INV_SCALE + vq + noise[rowoff + k];
                p[rowoff + k] = __builtin_amdgcn_rcpf(1.0f + __expf(-e));
            }
        }
    }
}

// ---------------------------------------------------------------------------
// 64-lane inclusive prefix sum via DPP (≈6 VALU ops)
// ---------------------------------------------------------------------------
__device__ __forceinline__ float wave_incl_scan(float x)
{
#define DPP_ADD(ctrl, rmask, bctrl)                                            \
    { int _t = __builtin_amdgcn_update_dpp(0, __builtin_bit_cast(int, x),      \
                                           ctrl, rmask, 0xf, bctrl);           \
      x += __builtin_bit_cast(float, _t); }
    DPP_ADD(0x111, 0xf, true)   // row_shr:1
    DPP_ADD(0x112, 0xf, true)   // row_shr:2
    DPP_ADD(0x114, 0xf, true)   // row_shr:4
    DPP_ADD(0x118, 0xf, true)   // row_shr:8
    DPP_ADD(0x142, 0xa, false)  // row_bcast:15 -> rows 1,3
    DPP_ADD(0x143, 0xc, false)  // row_bcast:31 -> rows 2,3
#undef DPP_ADD
    return x;
}

// Inclusive prefix over lanes 0..7 (valid in those lanes only; row_shr DPP).
__device__ __forceinline__ float row_prefix8(float x)
{
#define DPP_ADD(ctrl)                                                          \
    { int _t = __builtin_amdgcn_update_dpp(0, __builtin_bit_cast(int, x),      \
                                           ctrl, 0xf, 0xf, true);              \
      x += __builtin_bit_cast(float, _t); }
    DPP_ADD(0x111)   // row_shr:1
    DPP_ADD(0x112)   // row_shr:2
    DPP_ADD(0x114)   // row_shr:4
#undef DPP_ADD
    return x;
}

// ---------------------------------------------------------------------------
// cumprod_mr: per (b,q) row: cp = exp(excl_cumsum(log(clip(1-p)))); emits
// m = p*cp, r = 1/clip(cp).
// ---------------------------------------------------------------------------
__global__ __launch_bounds__(256) void cumprod_mr(
    const float* __restrict__ p, float* __restrict__ mArr, float* __restrict__ rArr)
{
    const size_t row = blockIdx.x;
    const float* pr = p + row * KLEN;
    float* mr = mArr + row * KLEN;
    float* rr = rArr + row * KLEN;
    const int tid = threadIdx.x;
    const int lane = tid & 63, wid = tid >> 6;
    __shared__ float waveTot[4];

    float4 v0 = *(const float4*)(pr + tid * 8);
    float4 v1 = *(const float4*)(pr + tid * 8 + 4);
    float pv[8] = {v0.x, v0.y, v0.z, v0.w, v1.x, v1.y, v1.z, v1.w};
    float excl[8];
    float run = 0.0f;
    #pragma unroll
    for (int j = 0; j < 8; ++j) {
        float l = __logf(fminf(fmaxf(1.0f - pv[j], EPSV), 1.0f));
        excl[j] = run;
        run += l;
    }
    float s = wave_incl_scan(run);
    if (lane == 63) waveTot[wid] = s;
    __syncthreads();
    float wex = 0.0f;
    for (int w = 0; w < wid; ++w) wex += waveTot[w];
    const float texcl = wex + s - run;

    float mv[8], rv[8];
    #pragma unroll
    for (int j = 0; j < 8; ++j) {
        const float cpv = __expf(texcl + excl[j]);
        mv[j] = pv[j] * cpv;
        rv[j] = __builtin_amdgcn_rcpf(fminf(fmaxf(cpv, EPSV), 1.0f));
    }
    *(float4*)(mr + tid * 8)     = *(float4*)&mv[0];
    *(float4*)(mr + tid * 8 + 4) = *(float4*)&mv[4];
    *(float4*)(rr + tid * 8)     = *(float4*)&rv[0];
    *(float4*)(rr + tid * 8 + 4) = *(float4*)&rv[4];
}

// ---------------------------------------------------------------------------
// alpha_echunk: FUSED kernel, 512 threads.
//  Blocks 0..7: alpha recurrence, TWO STEPS PER BARRIER.
//    R2-R6 established the cost is the write->barrier->read round-trip in
//    the dependency loop (~835cyc/step) and that the barrier structure
//    itself is the best-known shape. Linearity lets one barrier resolve two
//    steps: with u = m_i*r_{i+1}, and within-wave prefixes U (of u) and V
//    (of u*W_i) computed pre-barrier, T_{i+1,w} = C_{i,w}*TU_w + TV_w.
//    Each wave publishes (T_i, TU, TV) in one ds_write_b128; after ONE
//    barrier, lanes 0..7 read the 8 triples (conflict-free b128), a 3-DPP
//    row-prefix gives C_i, one fmaf + second prefix gives C_{i+1}; two
//    __shfl broadcasts deliver both bases. Epilogues: a_i = m_i(C_i+W_i),
//    W_{i+1} = C_i*U_full + V_full, a_{i+1} = m_{i+1}(C_{i+1}+W_{i+1}).
//    128 barriers instead of 256. All-f32 regrouping (numerically benign).
//    Slots double-buffered by pair parity (race-free under 1 barrier/pair).
//  Blocks 8..519: e_chunk via G: e[b,h] = qg_h[b] @ kx[b]^T (K=512),
//    8-wave 128x256 tiles, under alpha's shadow.
//  smem 96 KB -> 1 block/CU isolation for alpha (+4% proven, kept).
// ---------------------------------------------------------------------------
__global__ __launch_bounds__(512, 1) void alpha_echunk(
    const float* __restrict__ mArr, const float* __restrict__ rArr,
    float* __restrict__ alpha,
    const unsigned short* __restrict__ qg, const unsigned short* __restrict__ kx,
    float* __restrict__ out)
{
    __shared__ __align__(16) char smem[98304];   // 96 KB -> 1 block/CU
    const int bid = blockIdx.x;
    const int tid = threadIdx.x;

    if (bid < BATCH) {
        // -------- alpha scan: 2 steps per barrier --------
        __builtin_amdgcn_s_setprio(1);
        float* slots = (float*)smem;             // [2][8][4] floats
        const int lane = tid & 63, wid = tid >> 6;
        const float* mrow = mArr + (size_t)bid * QLEN * KLEN + tid * 4;
        const float* rrow = rArr + (size_t)bid * QLEN * KLEN + tid * 4;
        float* arow = alpha + (size_t)bid * QLEN * KLEN + tid * 4;

        float aw0 = 0.f, aw1 = 0.f, aw2 = 0.f, aw3 = 0.f;
        if (tid == 0) aw0 = 1.0f;   // aw_prev one-hot at k=0

        // set A = pair rows (0,1); set B = pair rows (2,3)
        float4 mP0 = *(const float4*)(mrow);
        float4 rP0 = *(const float4*)(rrow);
        float4 mP1 = *(const float4*)(mrow + KLEN);
        float4 rP1 = *(const float4*)(rrow + KLEN);
        float4 mQ0 = *(const float4*)(mrow + 2 * (size_t)KLEN);
        float4 rQ0 = *(const float4*)(rrow + 2 * (size_t)KLEN);
        float4 mQ1 = *(const float4*)(mrow + 3 * (size_t)KLEN);
        float4 rQ1 = *(const float4*)(rrow + 3 * (size_t)KLEN);

#define APAIR(I, M0, R0, M1, R1)                                               \
    {                                                                          \
        const int i_ = (I);                     /* even step index */          \
        float4 mc0 = M0, rc0 = R0, mc1 = M1, rc1 = R1;                         \
        const int rn_ = (i_ + 4 < QLEN) ? (i_ + 4) : (QLEN - 2);               \
        M0 = *(const float4*)(mrow + (size_t)rn_ * KLEN);                      \
        R0 = *(const float4*)(rrow + (size_t)rn_ * KLEN);                      \
        M1 = *(const float4*)(mrow + (size_t)(rn_ + 1) * KLEN);               \
        R1 = *(const float4*)(rrow + (size_t)(rn_ + 1) * KLEN);               \
        /* step i: x = aw * r_i, within-wave prefix */                         \
        float run = 0.f, i0, i1, i2, i3;                                       \
        run = fmaf(aw0, rc0.x, run); i0 = run;                                 \
        run = fmaf(aw1, rc0.y, run); i1 = run;                                 \
        run = fmaf(aw2, rc0.z, run); i2 = run;                                 \
        run = fmaf(aw3, rc0.w, run); i3 = run;                                 \
        const float sx = wave_incl_scan(run);                                  \
        const float wb = sx - run;                                             \
        const float W0 = wb + i0, W1 = wb + i1, W2 = wb + i2, W3 = wb + i3;    \
        /* u = m_i * r_{i+1}; prefixes U (of u) and V (of u*W) */              \
        const float u0 = mc0.x * rc1.x, u1 = mc0.y * rc1.y;                    \
        const float u2 = mc0.z * rc1.z, u3 = mc0.w * rc1.w;                    \
        float ur = u0;       const float U0 = ur;                              \
        ur += u1;            const float U1 = ur;                              \
        ur += u2;            const float U2 = ur;                              \
        ur += u3;            const float U3 = ur;                              \
        const float sU = wave_incl_scan(ur);                                   \
        const float ub = sU - ur;                                              \
        float vr = u0 * W0;              const float V0 = vr;                  \
        vr = fmaf(u1, W1, vr);           const float V1 = vr;                  \
        vr = fmaf(u2, W2, vr);           const float V2 = vr;                  \
        vr = fmaf(u3, W3, vr);           const float V3 = vr;                  \
        const float sV = wave_incl_scan(vr);                                   \
        const float vb = sV - vr;                                              \
        const int par = (i_ >> 1) & 1;                                         \
        if (lane == 63) {                                                      \
            float4 tv; tv.x = sx; tv.y = sU; tv.z = sV; tv.w = 0.f;            \
            *(float4*)(slots + (par * 8 + wid) * 4) = tv;                      \
        }                                                                      \
        lds_barrier();                                                         \
        float4 tr = *(const float4*)(slots + (par * 8 + (lane & 7)) * 4);      \
        const float pT = row_prefix8(tr.x);                                    \
        const float Cex = pT - tr.x;                                           \
        const float t2 = fmaf(Cex, tr.y, tr.z);                                \
        const float pQ = row_prefix8(t2);                                      \
        const float C2ex = pQ - t2;                                            \
        const float b0 = __shfl(Cex, wid);                                     \
        const float b1 = __shfl(C2ex, wid);                                    \
        /* epilogue step i */                                                  \
        float4 o0;                                                             \
        o0.x = mc0.x * (b0 + W0); o0.y = mc0.y * (b0 + W1);                    \
        o0.z = mc0.z * (b0 + W2); o0.w = mc0.w * (b0 + W3);                    \
        *(float4*)(arow + (size_t)i_ * KLEN) = o0;                             \
        /* epilogue step i+1 */                                                \
        const float X0 = fmaf(b0, ub + U0, vb + V0);                           \
        const float X1 = fmaf(b0, ub + U1, vb + V1);                           \
        const float X2 = fmaf(b0, ub + U2, vb + V2);                           \
        const float X3 = fmaf(b0, ub + U3, vb + V3);                           \
        aw0 = mc1.x * (b1 + X0); aw1 = mc1.y * (b1 + X1);                      \
        aw2 = mc1.z * (b1 + X2); aw3 = mc1.w * (b1 + X3);                      \
        float4 o1; o1.x = aw0; o1.y = aw1; o1.z = aw2; o1.w = aw3;             \
        *(float4*)(arow + (size_t)(i_ + 1) * KLEN) = o1;                       \
    }

        for (int io = 0; io < QLEN; io += 4) {
            APAIR(io + 0, mP0, rP0, mP1, rP1)
            APAIR(io + 2, mQ0, rQ0, mQ1, rQ1)
        }
#undef APAIR
        __builtin_amdgcn_s_setprio(0);
        return;
    }

    // -------- echunk tile: 8 waves, 128x256, K=512 --------
    const int v = bid - BATCH;           // 0..511
    const int z = v >> 4;                // 0..31 = b*4+h
    const int rest = v & 15;
    const int by = rest >> 3;            // 0..1
    const int bx = rest & 7;             // 0..7
    const int b = z >> 2, h = z & 3;
    unsigned short* As = (unsigned short*)smem;             // 8 KB (128x32)
    unsigned short* Bs = (unsigned short*)(smem + 8192);    // 16 KB (256x32)
    const unsigned short* A = qg + (size_t)(b * QLEN) * GCOLS + 512 + h * 512;
    const unsigned short* B = kx + (size_t)b * KLEN * 512;
    const int bm = by * 128, bn = bx * 256;

    const int wv8 = tid >> 6, ln = tid & 63;
    const int r = ln & 15, quad = ln >> 4;
    const int wr = wv8 >> 2, wc = wv8 & 3;
    const int srow = tid >> 2;           // 0..127
    const int scol = (ln & 3) * 8;

    f32x4 acc[4][4]; zero_acc(acc);
    for (int ks = 0; ks < 16; ++ks) {
        const int k0 = ks * 32;
        gload_lds16(A + (size_t)(bm + srow) * GCOLS + k0 + scol,
                    As + (size_t)wv8 * 512);
        gload_lds16(B + (size_t)(bn + srow) * 512 + k0 + scol,
                    Bs + (size_t)wv8 * 512);
        gload_lds16(B + (size_t)(bn + 128 + srow) * 512 + k0 + scol,
                    Bs + 4096 + (size_t)wv8 * 512);
        __syncthreads();
        bf16x8 af[4], bg[4];
        #pragma unroll
        for (int f = 0; f < 4; ++f)
            af[f] = *(const bf16x8*)(As + (size_t)(wr * 64 + f * 16 + r) * 32 + quad * 8);
        #pragma unroll
        for (int f = 0; f < 4; ++f)
            bg[f] = *(const bf16x8*)(Bs + (size_t)(wc * 64 + f * 16 + r) * 32 + quad * 8);
        #pragma unroll
        for (int i = 0; i < 4; ++i)
            #pragma unroll
            for (int j2 = 0; j2 < 4; ++j2)
                acc[i][j2] = __builtin_amdgcn_mfma_f32_16x16x32_bf16(
                    af[i], bg[j2], acc[i][j2], 0, 0, 0);
        __syncthreads();
    }
    {
        const int m0 = bm + wr * 64, n0 = bn + wc * 64;
        #pragma unroll
        for (int i = 0; i < 4; ++i) {
            #pragma unroll
            for (int reg = 0; reg < 4; ++reg) {
                const int q = m0 + i * 16 + quad * 4 + reg;
                const size_t rowoff = ((size_t)z * QLEN + q) * KLEN;
                #pragma unroll
                for (int j = 0; j < 4; ++j) {
                    const int k = n0 + j * 16 + r;
                    out[rowoff + k] = acc[i][j][reg] * INV_SCALE;
                }
            }
        }
    }
}

// ---------------------------------------------------------------------------
// beta: per (b,h,q) row of 2048 (e_chunk in d_out, overwritten)
// ---------------------------------------------------------------------------
__global__ __launch_bounds__(256) void beta_kernel(
    float* __restrict__ eo, const float* __restrict__ alpha)
{
    __shared__ float sse[KLEN + 3];
    __shared__ float su[KLEN + 3];
    __shared__ float wmax[4];

    const int tid = threadIdx.x;
    const int lane = tid & 63, wid = tid >> 6;
    const int row = blockIdx.x;                 // [B*H*Q]
    const int q = row & (QLEN - 1);
    const int b = row >> 10;
    float* erow = eo + (size_t)row * KLEN;
    const float* arow = alpha + ((size_t)b * QLEN + q) * KLEN;

    if (tid < 3) { sse[tid] = 0.0f; su[KLEN + tid] = 0.0f; }

    float ev[8];
    float lm = -INFINITY;
    #pragma unroll
    for (int j = 0; j < 8; ++j) {
        const int k = tid + 256 * j;
        ev[j] = erow[k];
        lm = fmaxf(lm, ev[j]);
    }
    #pragma unroll
    for (int off = 32; off > 0; off >>= 1) lm = fmaxf(lm, __shfl_xor(lm, off));
    if (lane == 0) wmax[wid] = lm;
    __syncthreads();
    const float mx = fmaxf(fmaxf(wmax[0], wmax[1]), fmaxf(wmax[2], wmax[3]));

    #pragma unroll
    for (int j = 0; j < 8; ++j) {
        const int k = tid + 256 * j;
        sse[k + 3] = fmaxf(__expf(ev[j] - mx), 1e-5f);
    }
    __syncthreads();

    #pragma unroll
    for (int j = 0; j < 8; ++j) {
        const int k = tid + 256 * j;
        const float denom = sse[k + 3] + sse[k + 2] + sse[k + 1] + sse[k];
        su[k] = arow[k] * __builtin_amdgcn_rcpf(denom);
    }
    __syncthreads();

    #pragma unroll
    for (int j = 0; j < 8; ++j) {
        const int k = tid + 256 * j;
        erow[k] = sse[k + 3] * (su[k] + su[k + 1] + su[k + 2] + su[k + 3]);
    }
}

// ---------------------------------------------------------------------------
extern "C" void kernel_launch(void* const* d_in, const int* in_sizes, int n_in,
                              void* d_out, int out_size, void* d_ws, size_t ws_size,
                              hipStream_t stream)
{
    (void)in_sizes; (void)n_in; (void)out_size; (void)ws_size;
    const float* key_enc = (const float*)d_in[0];   // [8,2048,512]
    const float* query   = (const float*)d_in[1];   // [8,256,512]
    const float* noise   = (const float*)d_in[2];   // [8,256,2048]
    const float* Wk_m    = (const float*)d_in[3];
    const float* bk_m    = (const float*)d_in[4];
    const float* Wq_m    = (const float*)d_in[5];
    const float* bq_m    = (const float*)d_in[6];
    const float* rp      = (const float*)d_in[7];
    const float* Wk_c    = (const float*)d_in[8];
    const float* bk_c    = (const float*)d_in[9];
    const float* Wq_c    = (const float*)d_in[10];
    const float* bq_c    = (const float*)d_in[11];
    float* out = (float*)d_out;                     // [8,4,256,2048]
    (void)bk_c;

    // workspace layout (bytes)
    char* w = (char*)d_ws;
    unsigned short* kx   = (unsigned short*)w; w += (size_t)BATCH * KLEN * KDIM * 2;  // 16.8 MB
    unsigned short* qx   = (unsigned short*)w; w += (size_t)QROWS * KDIM * 2;         //  2.1 MB
    unsigned short* kwm  = (unsigned short*)w; w += (size_t)512 * 512 * 2;
    unsigned short* kwc  = (unsigned short*)w; w += (size_t)512 * 512 * 2;
    unsigned short* qwm  = (unsigned short*)w; w += (size_t)512 * 512 * 2;
    unsigned short* qwc  = (unsigned short*)w; w += (size_t)512 * 512 * 2;
    unsigned short* GT   = (unsigned short*)w; w += (size_t)GCOLS * 512 * 2;          //  2.6 MB
    unsigned short* qg   = (unsigned short*)w; w += (size_t)QROWS * GCOLS * 2;        // 10.5 MB
    float* aux    = (float*)w; w += 4096 * 4;
    float* vq2    = (float*)w; w += QROWS * 4;
    float* p_alpha = (float*)w; w += (size_t)BATCH * QLEN * KLEN * 4;                 // 16.8 MB
    float* mArr    = (float*)w; w += (size_t)BATCH * QLEN * KLEN * 4;                 // 16.8 MB
    float* rArr    = (float*)w;                                                       // 16.8 MB

    // 1) casts (inputs + weights)
    hipLaunchKernelGGL(prep, dim3(NKXB + NQXB + 1024), dim3(256), 0, stream,
                       key_enc, query, Wk_m, Wk_c, Wq_m, Wq_c,
                       kx, qx, kwm, kwc, qwm, qwc);

    // 2) G matrices + bias-fold vectors (tiny)
    hipLaunchKernelGGL(smallg, dim3(93), dim3(256), 0, stream,
                       kwm, kwc, qwm, qwc, Wk_m, Wk_c, Wq_m,
                       bq_m, bk_m, bq_c, GT, aux);

    // 3) qg = qx @ GT^T + wv  (+ vq2)
    hipLaunchKernelGGL(qg_kernel, dim3(328), dim3(256), 0, stream,
                       qx, GT, aux, qg, vq2);

    // 4) p_choose
    hipLaunchKernelGGL(pchoose_mfma, dim3(KLEN / 128, QLEN / 128, BATCH), dim3(256), 0, stream,
                       qg, kx, noise, rp, vq2, p_alpha);

    // 5) cumprod -> (m, r)
    hipLaunchKernelGGL(cumprod_mr, dim3(BATCH * QLEN), dim3(256), 0, stream,
                       p_alpha, mArr, rArr);

    // 6) FUSED: alpha recurrence (blocks 0..7, 2-steps-per-barrier) +
    //           e_chunk (blocks 8..519)
    hipLaunchKernelGGL(alpha_echunk, dim3(BATCH + 512), dim3(512), 0, stream,
                       mArr, rArr, p_alpha, qg, kx, out);

    // 7) beta (overwrites e_chunk rows in d_out)
    hipLaunchKernelGGL(beta_kernel, dim3(BATCH * NHEADS * QLEN), dim3(256), 0, stream,
                       out, p_alpha);
}